// Round 3
// baseline (588.922 us; speedup 1.0000x reference)
//
#include <hip/hip_runtime.h>

#define NROWS 65536
#define DM 128

// ws layout in floats
#define WS_CKV  0        // 128*128 Gram matrix (written by reducer)
#define WS_SKEY 16384    // 128 col sums of key
#define WS_SVAL 16512    // 128 col sums of value
#define WS_W2   16640    // 128*128 folded phase-2 weight [k][c]
#define WS_B2   33024    // 128 folded phase-2 bias

// per-block partial layout in scratch (carved from d_out, overwritten by kernelC)
#define PART_STRIDE 16640   // 16384 tile + 128 skey + 128 sval

// ---------------------------------------------------------------------------
// Kernel A: per-block partial C = key_blk^T @ value_blk (128x128 fp32) +
// partial column sums. 256 blocks x 256 threads, 256 rows/block.
// Thread tile 16x4: lk reads are 32-lane broadcasts, lv reads unit-stride.
// NO global atomics: partials stored coalesced to scratch; kernelR reduces.
// ---------------------------------------------------------------------------
__global__ __launch_bounds__(256, 2) void kernelA(const float* __restrict__ key,
                                                  const float* __restrict__ value,
                                                  float* __restrict__ scratch) {
    __shared__ float lk[2][32 * 128];
    __shared__ float lv[2][32 * 128];
    __shared__ float red[256];

    const int tid = threadIdx.x;
    const int i0 = (tid >> 5) * 16;  // 0..112
    const int j0 = (tid & 31) * 4;   // 0..124
    const int row0 = blockIdx.x * 256;

    const float4* __restrict__ k4 = (const float4*)key;
    const float4* __restrict__ v4 = (const float4*)value;

    float acc[16][4];
#pragma unroll
    for (int a = 0; a < 16; ++a)
#pragma unroll
        for (int b = 0; b < 4; ++b) acc[a][b] = 0.f;

    float sk[4] = {0.f, 0.f, 0.f, 0.f};
    float sv[4] = {0.f, 0.f, 0.f, 0.f};

    float4 rk[4], rv[4];
    // prologue: tile 0 (rows row0..row0+31); 1024 float4 per array, 4/thread
    {
        const int g = row0 * 32;
#pragma unroll
        for (int q = 0; q < 4; ++q) { rk[q] = k4[g + tid + 256 * q]; rv[q] = v4[g + tid + 256 * q]; }
#pragma unroll
        for (int q = 0; q < 4; ++q) {
            ((float4*)lk[0])[tid + 256 * q] = rk[q];
            ((float4*)lv[0])[tid + 256 * q] = rv[q];
            sk[0] += rk[q].x; sk[1] += rk[q].y; sk[2] += rk[q].z; sk[3] += rk[q].w;
            sv[0] += rv[q].x; sv[1] += rv[q].y; sv[2] += rv[q].z; sv[3] += rv[q].w;
        }
    }
    __syncthreads();

    for (int t = 0; t < 8; ++t) {
        const int cur = t & 1;
        if (t < 7) {  // prefetch next tile
            const int g = (row0 + (t + 1) * 32) * 32;
#pragma unroll
            for (int q = 0; q < 4; ++q) { rk[q] = k4[g + tid + 256 * q]; rv[q] = v4[g + tid + 256 * q]; }
        }
#pragma unroll 4
        for (int kk = 0; kk < 32; ++kk) {
            float ka[16], vb[4];
            *(float4*)&ka[0]  = *(const float4*)&lk[cur][kk * 128 + i0];
            *(float4*)&ka[4]  = *(const float4*)&lk[cur][kk * 128 + i0 + 4];
            *(float4*)&ka[8]  = *(const float4*)&lk[cur][kk * 128 + i0 + 8];
            *(float4*)&ka[12] = *(const float4*)&lk[cur][kk * 128 + i0 + 12];
            *(float4*)&vb[0]  = *(const float4*)&lv[cur][kk * 128 + j0];
#pragma unroll
            for (int a = 0; a < 16; ++a)
#pragma unroll
                for (int b = 0; b < 4; ++b)
                    acc[a][b] = fmaf(ka[a], vb[b], acc[a][b]);
        }
        if (t < 7) {
            const int nxt = cur ^ 1;
#pragma unroll
            for (int q = 0; q < 4; ++q) {
                ((float4*)lk[nxt])[tid + 256 * q] = rk[q];
                ((float4*)lv[nxt])[tid + 256 * q] = rv[q];
                sk[0] += rk[q].x; sk[1] += rk[q].y; sk[2] += rk[q].z; sk[3] += rk[q].w;
                sv[0] += rv[q].x; sv[1] += rv[q].y; sv[2] += rv[q].z; sv[3] += rv[q].w;
            }
            __syncthreads();
        }
    }

    // LDS-reduce colsums (loaded float4 cols are (tid&31)*4 .. +3)
    red[tid] = 0.f;
    __syncthreads();
    const int cg = (tid & 31) * 4;
#pragma unroll
    for (int a = 0; a < 4; ++a) {
        atomicAdd(&red[cg + a], sk[a]);
        atomicAdd(&red[128 + cg + a], sv[a]);
    }
    __syncthreads();

    // store partial tile + colsums, fully coalesced
    float* __restrict__ part = scratch + (size_t)blockIdx.x * PART_STRIDE;
#pragma unroll
    for (int ii = 0; ii < 16; ++ii) {
        float4 s; s.x = acc[ii][0]; s.y = acc[ii][1]; s.z = acc[ii][2]; s.w = acc[ii][3];
        *(float4*)&part[(i0 + ii) * 128 + j0] = s;
    }
    part[16384 + tid] = red[tid];
}

// ---------------------------------------------------------------------------
// Kernel R: sum 256 partials -> ws[0..16640). e<16384: Ckv; then skey, sval.
// ---------------------------------------------------------------------------
__global__ __launch_bounds__(128) void kernelR(const float* __restrict__ scratch,
                                               float* __restrict__ ws) {
    const int e = blockIdx.x * 128 + threadIdx.x;  // 130*128 = 16640 exact
    float s0 = 0.f, s1 = 0.f, s2 = 0.f, s3 = 0.f;
    for (int b = 0; b < 256; b += 4) {
        s0 += scratch[(size_t)(b + 0) * PART_STRIDE + e];
        s1 += scratch[(size_t)(b + 1) * PART_STRIDE + e];
        s2 += scratch[(size_t)(b + 2) * PART_STRIDE + e];
        s3 += scratch[(size_t)(b + 3) * PART_STRIDE + e];
    }
    ws[e] = (s0 + s1) + (s2 + s3);
}

// ---------------------------------------------------------------------------
// Kernel B: per-head (4 blocks x 256 threads):
//   T = C @ Wv_h^T            (128 x 32)
//   p_h[d][e] = (Wk_h T + (Wk_h s_k) bv^T + bk (Wv_h s_v)^T + N bk bv^T)/N
//   W2[:, h*32+e] = sum_d Wq[h*32+d,:] p_h[d][e];  b2 = bq_h @ p_h
// Writes p_attn to out tail and W2 [k][c] / b2 to ws.
// ---------------------------------------------------------------------------
__global__ void kernelB(const float* __restrict__ Wk, const float* __restrict__ bk,
                        const float* __restrict__ Wv, const float* __restrict__ bv,
                        const float* __restrict__ Wq, const float* __restrict__ bq,
                        float* __restrict__ ws, float* __restrict__ out) {
    __shared__ float ckv[128 * 128];  // [i][j]
    __shared__ float wvT[128 * 32];   // [j][e]
    __shared__ float wk_s[32 * 128];  // [d][i]
    __shared__ float wq_s[32 * 128];  // [d][i]
    __shared__ float Tl[128 * 32];    // [i][e]
    __shared__ float pl[32 * 32];     // [d][e]
    __shared__ float skey[128], sval[128];
    __shared__ float bk_s[32], bv_s[32], bq_s[32];
    __shared__ float wvec[32], uvec[32];

    const int tid = threadIdx.x;
    const int h = blockIdx.x;

    const float4* __restrict__ ws4 = (const float4*)ws;
    const float4* __restrict__ Wk4 = (const float4*)Wk;
    const float4* __restrict__ Wq4 = (const float4*)Wq;
    const float4* __restrict__ Wv4 = (const float4*)Wv;

#pragma unroll
    for (int q = 0; q < 16; ++q)
        ((float4*)ckv)[tid + 256 * q] = ws4[(WS_CKV >> 2) + tid + 256 * q];
#pragma unroll
    for (int q = 0; q < 4; ++q) {
        ((float4*)wk_s)[tid + 256 * q] = Wk4[h * 1024 + tid + 256 * q];
        ((float4*)wq_s)[tid + 256 * q] = Wq4[h * 1024 + tid + 256 * q];
    }
#pragma unroll
    for (int q = 0; q < 4; ++q) {
        const int f = tid + 256 * q;
        const int e = f >> 5;
        const int c = (f & 31) * 4;
        float4 v = Wv4[h * 1024 + f];
        wvT[(c + 0) * 32 + e] = v.x;
        wvT[(c + 1) * 32 + e] = v.y;
        wvT[(c + 2) * 32 + e] = v.z;
        wvT[(c + 3) * 32 + e] = v.w;
    }
    if (tid < 128) { skey[tid] = ws[WS_SKEY + tid]; sval[tid] = ws[WS_SVAL + tid]; }
    if (tid < 32) { bk_s[tid] = bk[h * 32 + tid]; bv_s[tid] = bv[h * 32 + tid]; bq_s[tid] = bq[h * 32 + tid]; }
    __syncthreads();

    const int e = tid & 31;
    const int ib = (tid >> 5) * 16;
    {
        float accT[16] = {};
        for (int j = 0; j < 128; ++j) {
            const float wv = wvT[j * 32 + e];
#pragma unroll
            for (int ii = 0; ii < 16; ++ii)
                accT[ii] = fmaf(ckv[(ib + ii) * 128 + j], wv, accT[ii]);
        }
#pragma unroll
        for (int ii = 0; ii < 16; ++ii) Tl[(ib + ii) * 32 + e] = accT[ii];

        if (tid < 32) {
            float u = 0.f;
            for (int j = 0; j < 128; ++j) u = fmaf(wvT[j * 32 + tid], sval[j], u);
            uvec[tid] = u;
        } else if (tid < 64) {
            const int a = tid - 32;
            float w = 0.f;
            for (int i = 0; i < 128; ++i) w = fmaf(wk_s[a * 128 + i], skey[i], w);
            wvec[a] = w;
        }
    }
    __syncthreads();
    {
        const int d0 = tid >> 5;  // 0..7
        float accP[4] = {};
        for (int i = 0; i < 128; ++i) {
            const float tv = Tl[i * 32 + e];
#pragma unroll
            for (int r = 0; r < 4; ++r)
                accP[r] = fmaf(wk_s[(d0 + 8 * r) * 128 + i], tv, accP[r]);
        }
#pragma unroll
        for (int r = 0; r < 4; ++r) {
            const int d = d0 + 8 * r;
            const float p = (accP[r] + wvec[d] * bv_s[e] + bk_s[d] * uvec[e] +
                             65536.f * bk_s[d] * bv_s[e]) * (1.f / 65536.f);
            pl[d * 32 + e] = p;
            out[8388608 + h * 1024 + d * 32 + e] = p;
        }
    }
    __syncthreads();
    {
        float accW[16] = {};
        for (int d = 0; d < 32; ++d) {
            const float pv = pl[d * 32 + e];
#pragma unroll
            for (int ii = 0; ii < 16; ++ii)
                accW[ii] = fmaf(wq_s[d * 128 + (ib + ii)], pv, accW[ii]);
        }
#pragma unroll
        for (int ii = 0; ii < 16; ++ii)
            ws[WS_W2 + (ib + ii) * 128 + h * 32 + e] = accW[ii];

        if (tid < 32) {
            float b2v = 0.f;
#pragma unroll
            for (int d = 0; d < 32; ++d) b2v = fmaf(bq_s[d], pl[d * 32 + tid], b2v);
            ws[WS_B2 + h * 32 + tid] = b2v;
        }
    }
}

// ---------------------------------------------------------------------------
// Kernel C: x = query @ W2 + b2, stored transposed: out[c*65536 + n] = x[n][c].
// 256 blocks x 512 threads, 256 rows/block. Wave w owns columns w*16..w*16+15;
// lane nl=tid&63 owns rows nl*4..+3  =>  every store instruction writes 1 KB
// contiguous in one output column (full-line writes, no RMW).
// ---------------------------------------------------------------------------
__global__ __launch_bounds__(512, 4) void kernelC(const float* __restrict__ query,
                                                  const float* __restrict__ ws,
                                                  float* __restrict__ out) {
    __shared__ float qT[2][16][256];   // [k][n]
    __shared__ float w2s[2][16][128];  // [k][c]
    __shared__ float b2s[128];

    const int tid = threadIdx.x;
    const int nl = tid & 63;    // n offset = nl*4
    const int w = tid >> 6;     // wave id; c base = w*16
    const int rowbase = blockIdx.x * 256;
    const int nrow = tid >> 1;  // staging row 0..255
    const int half = tid & 1;

    const float4* __restrict__ q4 = (const float4*)query;
    const float4* __restrict__ w24 = (const float4*)(ws + WS_W2);

    if (tid < 32) ((float4*)b2s)[tid] = ((const float4*)(ws + WS_B2))[tid];

    float acc[16][4];
#pragma unroll
    for (int a = 0; a < 16; ++a)
#pragma unroll
        for (int b = 0; b < 4; ++b) acc[a][b] = 0.f;

    float4 rq0, rq1, rw;
    // prologue: kc = 0
    rq0 = q4[(rowbase + nrow) * 32 + half * 2 + 0];
    rq1 = q4[(rowbase + nrow) * 32 + half * 2 + 1];
    rw = w24[tid];
    {
        const int kp = half * 8;
        qT[0][kp + 0][nrow] = rq0.x; qT[0][kp + 1][nrow] = rq0.y;
        qT[0][kp + 2][nrow] = rq0.z; qT[0][kp + 3][nrow] = rq0.w;
        qT[0][kp + 4][nrow] = rq1.x; qT[0][kp + 5][nrow] = rq1.y;
        qT[0][kp + 6][nrow] = rq1.z; qT[0][kp + 7][nrow] = rq1.w;
        ((float4*)w2s[0])[tid] = rw;
    }
    __syncthreads();

    for (int kc = 0; kc < 8; ++kc) {
        const int cur = kc & 1;
        if (kc < 7) {
            rq0 = q4[(rowbase + nrow) * 32 + (kc + 1) * 4 + half * 2 + 0];
            rq1 = q4[(rowbase + nrow) * 32 + (kc + 1) * 4 + half * 2 + 1];
            rw = w24[(kc + 1) * 512 + tid];
        }
#pragma unroll
        for (int k = 0; k < 16; ++k) {
            float qv[4], wv[16];
            *(float4*)&qv[0]  = *(const float4*)&qT[cur][k][nl * 4];
            *(float4*)&wv[0]  = *(const float4*)&w2s[cur][k][w * 16 + 0];
            *(float4*)&wv[4]  = *(const float4*)&w2s[cur][k][w * 16 + 4];
            *(float4*)&wv[8]  = *(const float4*)&w2s[cur][k][w * 16 + 8];
            *(float4*)&wv[12] = *(const float4*)&w2s[cur][k][w * 16 + 12];
#pragma unroll
            for (int i = 0; i < 16; ++i)
#pragma unroll
                for (int j = 0; j < 4; ++j)
                    acc[i][j] = fmaf(wv[i], qv[j], acc[i][j]);
        }
        if (kc < 7) {
            const int nxt = cur ^ 1;
            const int kp = half * 8;
            qT[nxt][kp + 0][nrow] = rq0.x; qT[nxt][kp + 1][nrow] = rq0.y;
            qT[nxt][kp + 2][nrow] = rq0.z; qT[nxt][kp + 3][nrow] = rq0.w;
            qT[nxt][kp + 4][nrow] = rq1.x; qT[nxt][kp + 5][nrow] = rq1.y;
            qT[nxt][kp + 6][nrow] = rq1.z; qT[nxt][kp + 7][nrow] = rq1.w;
            ((float4*)w2s[nxt])[tid] = rw;
            __syncthreads();
        }
    }

    // epilogue: per instruction, 64 lanes x float4 = 1 KB contiguous per column
#pragma unroll
    for (int i = 0; i < 16; ++i) {
        const int c = w * 16 + i;
        const float bb = b2s[c];
        float4 s;
        s.x = acc[i][0] + bb; s.y = acc[i][1] + bb;
        s.z = acc[i][2] + bb; s.w = acc[i][3] + bb;
        *(float4*)(out + (size_t)c * 65536 + rowbase + nl * 4) = s;
    }
}

extern "C" void kernel_launch(void* const* d_in, const int* in_sizes, int n_in,
                              void* d_out, int out_size, void* d_ws, size_t ws_size,
                              hipStream_t stream) {
    const float* query = (const float*)d_in[0];
    const float* key   = (const float*)d_in[1];
    const float* value = (const float*)d_in[2];
    const float* Wq = (const float*)d_in[3];
    const float* bq = (const float*)d_in[4];
    const float* Wk = (const float*)d_in[5];
    const float* bk = (const float*)d_in[6];
    const float* Wv = (const float*)d_in[7];
    const float* bv = (const float*)d_in[8];
    float* out = (float*)d_out;
    float* ws  = (float*)d_ws;
    float* scratch = out;  // partials region (256*16640 floats < 8388608), overwritten by kernelC

    hipLaunchKernelGGL(kernelA, dim3(256), dim3(256), 0, stream, key, value, scratch);
    hipLaunchKernelGGL(kernelR, dim3(130), dim3(128), 0, stream, scratch, ws);
    hipLaunchKernelGGL(kernelB, dim3(4), dim3(256), 0, stream, Wk, bk, Wv, bv, Wq, bq, ws, out);
    hipLaunchKernelGGL(kernelC, dim3(256), dim3(512), 0, stream, query, ws, out);
}

// Round 4
// 229.491 us; speedup vs baseline: 2.5662x; 2.5662x over previous
//
#include <hip/hip_runtime.h>

#define NROWS 65536
#define DM 128

// ws layout in floats
#define WS_CKV  0        // 128*128 Gram matrix (written by reducer)
#define WS_SKEY 16384    // 128 col sums of key
#define WS_SVAL 16512    // 128 col sums of value
#define WS_W2   16640    // 128*128 folded phase-2 weight [k][c]
#define WS_B2   33024    // 128 folded phase-2 bias

// per-block partial layout in scratch (carved from d_out, overwritten by kernelC)
#define PART_STRIDE 16896   // 16384 tile + 128 skey + 128 sval + pad to x256

// ---------------------------------------------------------------------------
// Kernel A: per-block partial C = key_blk^T @ value_blk (128x128 fp32) +
// partial column sums. 256 blocks x 256 threads, 256 rows/block.
// Thread tile 16x4: lk reads are 32-lane broadcasts, lv reads unit-stride.
// NO global atomics: partials stored coalesced to scratch; kernelR reduces.
// ---------------------------------------------------------------------------
__global__ __launch_bounds__(256, 2) void kernelA(const float* __restrict__ key,
                                                  const float* __restrict__ value,
                                                  float* __restrict__ scratch) {
    __shared__ float lk[2][32 * 128];
    __shared__ float lv[2][32 * 128];
    __shared__ float red[256];

    const int tid = threadIdx.x;
    const int i0 = (tid >> 5) * 16;  // 0..112
    const int j0 = (tid & 31) * 4;   // 0..124
    const int row0 = blockIdx.x * 256;

    const float4* __restrict__ k4 = (const float4*)key;
    const float4* __restrict__ v4 = (const float4*)value;

    float acc[16][4];
#pragma unroll
    for (int a = 0; a < 16; ++a)
#pragma unroll
        for (int b = 0; b < 4; ++b) acc[a][b] = 0.f;

    float sk[4] = {0.f, 0.f, 0.f, 0.f};
    float sv[4] = {0.f, 0.f, 0.f, 0.f};

    float4 rk[4], rv[4];
    // prologue: tile 0 (rows row0..row0+31); 1024 float4 per array, 4/thread
    {
        const int g = row0 * 32;
#pragma unroll
        for (int q = 0; q < 4; ++q) { rk[q] = k4[g + tid + 256 * q]; rv[q] = v4[g + tid + 256 * q]; }
#pragma unroll
        for (int q = 0; q < 4; ++q) {
            ((float4*)lk[0])[tid + 256 * q] = rk[q];
            ((float4*)lv[0])[tid + 256 * q] = rv[q];
            sk[0] += rk[q].x; sk[1] += rk[q].y; sk[2] += rk[q].z; sk[3] += rk[q].w;
            sv[0] += rv[q].x; sv[1] += rv[q].y; sv[2] += rv[q].z; sv[3] += rv[q].w;
        }
    }
    __syncthreads();

    for (int t = 0; t < 8; ++t) {
        const int cur = t & 1;
        if (t < 7) {  // prefetch next tile
            const int g = (row0 + (t + 1) * 32) * 32;
#pragma unroll
            for (int q = 0; q < 4; ++q) { rk[q] = k4[g + tid + 256 * q]; rv[q] = v4[g + tid + 256 * q]; }
        }
#pragma unroll 4
        for (int kk = 0; kk < 32; ++kk) {
            float ka[16], vb[4];
            *(float4*)&ka[0]  = *(const float4*)&lk[cur][kk * 128 + i0];
            *(float4*)&ka[4]  = *(const float4*)&lk[cur][kk * 128 + i0 + 4];
            *(float4*)&ka[8]  = *(const float4*)&lk[cur][kk * 128 + i0 + 8];
            *(float4*)&ka[12] = *(const float4*)&lk[cur][kk * 128 + i0 + 12];
            *(float4*)&vb[0]  = *(const float4*)&lv[cur][kk * 128 + j0];
#pragma unroll
            for (int a = 0; a < 16; ++a)
#pragma unroll
                for (int b = 0; b < 4; ++b)
                    acc[a][b] = fmaf(ka[a], vb[b], acc[a][b]);
        }
        if (t < 7) {
            const int nxt = cur ^ 1;
#pragma unroll
            for (int q = 0; q < 4; ++q) {
                ((float4*)lk[nxt])[tid + 256 * q] = rk[q];
                ((float4*)lv[nxt])[tid + 256 * q] = rv[q];
                sk[0] += rk[q].x; sk[1] += rk[q].y; sk[2] += rk[q].z; sk[3] += rk[q].w;
                sv[0] += rv[q].x; sv[1] += rv[q].y; sv[2] += rv[q].z; sv[3] += rv[q].w;
            }
            __syncthreads();
        }
    }

    // LDS-reduce colsums (loaded float4 cols are (tid&31)*4 .. +3)
    red[tid] = 0.f;
    __syncthreads();
    const int cg = (tid & 31) * 4;
#pragma unroll
    for (int a = 0; a < 4; ++a) {
        atomicAdd(&red[cg + a], sk[a]);
        atomicAdd(&red[128 + cg + a], sv[a]);
    }
    __syncthreads();

    // store partial tile + colsums, fully coalesced
    float* __restrict__ part = scratch + (size_t)blockIdx.x * PART_STRIDE;
#pragma unroll
    for (int ii = 0; ii < 16; ++ii) {
        float4 s; s.x = acc[ii][0]; s.y = acc[ii][1]; s.z = acc[ii][2]; s.w = acc[ii][3];
        *(float4*)&part[(i0 + ii) * 128 + j0] = s;
    }
    part[16384 + tid] = red[tid];
}

// ---------------------------------------------------------------------------
// Kernel R: sum 256 partials -> ws[0..16640). 260 blocks x 256 threads;
// block b owns elements 64b..64b+63; thread group tid>>6 sums a 64-partial
// slice with 8 independent chains; LDS combine. All loads 256B-coalesced.
// ---------------------------------------------------------------------------
__global__ __launch_bounds__(256) void kernelR(const float* __restrict__ scratch,
                                               float* __restrict__ ws) {
    __shared__ float red[4][64];
    const int tid = threadIdx.x;
    const int e = blockIdx.x * 64 + (tid & 63);
    const int p0 = (tid >> 6) * 64;

    float s0 = 0.f, s1 = 0.f, s2 = 0.f, s3 = 0.f;
    float s4 = 0.f, s5 = 0.f, s6 = 0.f, s7 = 0.f;
    for (int p = p0; p < p0 + 64; p += 8) {
        s0 += scratch[(size_t)(p + 0) * PART_STRIDE + e];
        s1 += scratch[(size_t)(p + 1) * PART_STRIDE + e];
        s2 += scratch[(size_t)(p + 2) * PART_STRIDE + e];
        s3 += scratch[(size_t)(p + 3) * PART_STRIDE + e];
        s4 += scratch[(size_t)(p + 4) * PART_STRIDE + e];
        s5 += scratch[(size_t)(p + 5) * PART_STRIDE + e];
        s6 += scratch[(size_t)(p + 6) * PART_STRIDE + e];
        s7 += scratch[(size_t)(p + 7) * PART_STRIDE + e];
    }
    red[tid >> 6][tid & 63] = ((s0 + s1) + (s2 + s3)) + ((s4 + s5) + (s6 + s7));
    __syncthreads();
    if (tid < 64)
        ws[blockIdx.x * 64 + tid] = (red[0][tid] + red[1][tid]) + (red[2][tid] + red[3][tid]);
}

// ---------------------------------------------------------------------------
// Kernel B: per-head (4 blocks x 256 threads):
//   T = C @ Wv_h^T            (128 x 32)
//   p_h[d][e] = (Wk_h T + (Wk_h s_k) bv^T + bk (Wv_h s_v)^T + N bk bv^T)/N
//   W2[:, h*32+e] = sum_d Wq[h*32+d,:] p_h[d][e];  b2 = bq_h @ p_h
// Writes p_attn to out tail and W2 [k][c] / b2 to ws.
// ---------------------------------------------------------------------------
__global__ void kernelB(const float* __restrict__ Wk, const float* __restrict__ bk,
                        const float* __restrict__ Wv, const float* __restrict__ bv,
                        const float* __restrict__ Wq, const float* __restrict__ bq,
                        float* __restrict__ ws, float* __restrict__ out) {
    __shared__ float ckv[128 * 128];  // [i][j]
    __shared__ float wvT[128 * 32];   // [j][e]
    __shared__ float wk_s[32 * 128];  // [d][i]
    __shared__ float wq_s[32 * 128];  // [d][i]
    __shared__ float Tl[128 * 32];    // [i][e]
    __shared__ float pl[32 * 32];     // [d][e]
    __shared__ float skey[128], sval[128];
    __shared__ float bk_s[32], bv_s[32], bq_s[32];
    __shared__ float wvec[32], uvec[32];

    const int tid = threadIdx.x;
    const int h = blockIdx.x;

    const float4* __restrict__ ws4 = (const float4*)ws;
    const float4* __restrict__ Wk4 = (const float4*)Wk;
    const float4* __restrict__ Wq4 = (const float4*)Wq;
    const float4* __restrict__ Wv4 = (const float4*)Wv;

#pragma unroll
    for (int q = 0; q < 16; ++q)
        ((float4*)ckv)[tid + 256 * q] = ws4[(WS_CKV >> 2) + tid + 256 * q];
#pragma unroll
    for (int q = 0; q < 4; ++q) {
        ((float4*)wk_s)[tid + 256 * q] = Wk4[h * 1024 + tid + 256 * q];
        ((float4*)wq_s)[tid + 256 * q] = Wq4[h * 1024 + tid + 256 * q];
    }
#pragma unroll
    for (int q = 0; q < 4; ++q) {
        const int f = tid + 256 * q;
        const int e = f >> 5;
        const int c = (f & 31) * 4;
        float4 v = Wv4[h * 1024 + f];
        wvT[(c + 0) * 32 + e] = v.x;
        wvT[(c + 1) * 32 + e] = v.y;
        wvT[(c + 2) * 32 + e] = v.z;
        wvT[(c + 3) * 32 + e] = v.w;
    }
    if (tid < 128) { skey[tid] = ws[WS_SKEY + tid]; sval[tid] = ws[WS_SVAL + tid]; }
    if (tid < 32) { bk_s[tid] = bk[h * 32 + tid]; bv_s[tid] = bv[h * 32 + tid]; bq_s[tid] = bq[h * 32 + tid]; }
    __syncthreads();

    const int e = tid & 31;
    const int ib = (tid >> 5) * 16;
    {
        float accT[16] = {};
        for (int j = 0; j < 128; ++j) {
            const float wv = wvT[j * 32 + e];
#pragma unroll
            for (int ii = 0; ii < 16; ++ii)
                accT[ii] = fmaf(ckv[(ib + ii) * 128 + j], wv, accT[ii]);
        }
#pragma unroll
        for (int ii = 0; ii < 16; ++ii) Tl[(ib + ii) * 32 + e] = accT[ii];

        if (tid < 32) {
            float u = 0.f;
            for (int j = 0; j < 128; ++j) u = fmaf(wvT[j * 32 + tid], sval[j], u);
            uvec[tid] = u;
        } else if (tid < 64) {
            const int a = tid - 32;
            float w = 0.f;
            for (int i = 0; i < 128; ++i) w = fmaf(wk_s[a * 128 + i], skey[i], w);
            wvec[a] = w;
        }
    }
    __syncthreads();
    {
        const int d0 = tid >> 5;  // 0..7
        float accP[4] = {};
        for (int i = 0; i < 128; ++i) {
            const float tv = Tl[i * 32 + e];
#pragma unroll
            for (int r = 0; r < 4; ++r)
                accP[r] = fmaf(wk_s[(d0 + 8 * r) * 128 + i], tv, accP[r]);
        }
#pragma unroll
        for (int r = 0; r < 4; ++r) {
            const int d = d0 + 8 * r;
            const float p = (accP[r] + wvec[d] * bv_s[e] + bk_s[d] * uvec[e] +
                             65536.f * bk_s[d] * bv_s[e]) * (1.f / 65536.f);
            pl[d * 32 + e] = p;
            out[8388608 + h * 1024 + d * 32 + e] = p;
        }
    }
    __syncthreads();
    {
        float accW[16] = {};
        for (int d = 0; d < 32; ++d) {
            const float pv = pl[d * 32 + e];
#pragma unroll
            for (int ii = 0; ii < 16; ++ii)
                accW[ii] = fmaf(wq_s[d * 128 + (ib + ii)], pv, accW[ii]);
        }
#pragma unroll
        for (int ii = 0; ii < 16; ++ii)
            ws[WS_W2 + (ib + ii) * 128 + h * 32 + e] = accW[ii];

        if (tid < 32) {
            float b2v = 0.f;
#pragma unroll
            for (int d = 0; d < 32; ++d) b2v = fmaf(bq_s[d], pl[d * 32 + tid], b2v);
            ws[WS_B2 + h * 32 + tid] = b2v;
        }
    }
}

// ---------------------------------------------------------------------------
// Kernel C: x = query @ W2 + b2, stored transposed: out[c*65536 + n] = x[n][c].
// Grid 512 = 128 row-blocks x 2 col-halves; 512 threads. Block = 256 rows x
// 64 cols. Wave w owns 8 cols (broadcast wv reads); lane owns 4 rows.
// acc[8][4] = 32 regs -> no spill. Stores: 64 lanes x float4 = 1 KB
// contiguous per column per instruction (full-line writes).
// ---------------------------------------------------------------------------
__global__ __launch_bounds__(512, 2) void kernelC(const float* __restrict__ query,
                                                  const float* __restrict__ ws,
                                                  float* __restrict__ out) {
    __shared__ float qT[2][16][256];   // [k][n]
    __shared__ float w2s[2][16][64];   // [k][c within half]
    __shared__ float b2s[64];

    const int tid = threadIdx.x;
    const int nl = tid & 63;           // row offset = nl*4
    const int w = tid >> 6;            // wave 0..7; cols cb..cb+7
    const int cb = w * 8;
    const int rowbase = (blockIdx.x >> 1) * 256;
    const int ch = blockIdx.x & 1;     // column half (0: cols 0-63, 1: 64-127)
    const int nrow = tid >> 1;         // staging row 0..255
    const int half = tid & 1;

    const float4* __restrict__ q4 = (const float4*)query;
    const float4* __restrict__ w24 = (const float4*)(ws + WS_W2);

    if (tid < 16) ((float4*)b2s)[tid] = ((const float4*)(ws + WS_B2 + ch * 64))[tid];

    float acc[8][4];
#pragma unroll
    for (int a = 0; a < 8; ++a)
#pragma unroll
        for (int b = 0; b < 4; ++b) acc[a][b] = 0.f;

    float4 rq0, rq1, rw;
    // prologue: kc = 0
    rq0 = q4[(rowbase + nrow) * 32 + half * 2 + 0];
    rq1 = q4[(rowbase + nrow) * 32 + half * 2 + 1];
    if (tid < 256) rw = w24[(tid >> 4) * 32 + ch * 16 + (tid & 15)];
    {
        const int kp = half * 8;
        qT[0][kp + 0][nrow] = rq0.x; qT[0][kp + 1][nrow] = rq0.y;
        qT[0][kp + 2][nrow] = rq0.z; qT[0][kp + 3][nrow] = rq0.w;
        qT[0][kp + 4][nrow] = rq1.x; qT[0][kp + 5][nrow] = rq1.y;
        qT[0][kp + 6][nrow] = rq1.z; qT[0][kp + 7][nrow] = rq1.w;
        if (tid < 256) ((float4*)w2s[0])[tid] = rw;
    }
    __syncthreads();

    for (int kc = 0; kc < 8; ++kc) {
        const int cur = kc & 1;
        if (kc < 7) {
            rq0 = q4[(rowbase + nrow) * 32 + (kc + 1) * 4 + half * 2 + 0];
            rq1 = q4[(rowbase + nrow) * 32 + (kc + 1) * 4 + half * 2 + 1];
            if (tid < 256) rw = w24[((kc + 1) * 16 + (tid >> 4)) * 32 + ch * 16 + (tid & 15)];
        }
#pragma unroll
        for (int k = 0; k < 16; ++k) {
            float qv[4], wv[8];
            *(float4*)&qv[0] = *(const float4*)&qT[cur][k][nl * 4];
            *(float4*)&wv[0] = *(const float4*)&w2s[cur][k][cb];      // wave-uniform (broadcast)
            *(float4*)&wv[4] = *(const float4*)&w2s[cur][k][cb + 4];
#pragma unroll
            for (int i = 0; i < 8; ++i)
#pragma unroll
                for (int j = 0; j < 4; ++j)
                    acc[i][j] = fmaf(wv[i], qv[j], acc[i][j]);
        }
        if (kc < 7) {
            const int nxt = cur ^ 1;
            const int kp = half * 8;
            qT[nxt][kp + 0][nrow] = rq0.x; qT[nxt][kp + 1][nrow] = rq0.y;
            qT[nxt][kp + 2][nrow] = rq0.z; qT[nxt][kp + 3][nrow] = rq0.w;
            qT[nxt][kp + 4][nrow] = rq1.x; qT[nxt][kp + 5][nrow] = rq1.y;
            qT[nxt][kp + 6][nrow] = rq1.z; qT[nxt][kp + 7][nrow] = rq1.w;
            if (tid < 256) ((float4*)w2s[nxt])[tid] = rw;
            __syncthreads();
        }
    }

    // epilogue: per instruction, 64 lanes x float4 = 1 KB contiguous per column
#pragma unroll
    for (int i = 0; i < 8; ++i) {
        const int c = ch * 64 + cb + i;
        const float bb = b2s[cb + i];
        float4 s;
        s.x = acc[i][0] + bb; s.y = acc[i][1] + bb;
        s.z = acc[i][2] + bb; s.w = acc[i][3] + bb;
        *(float4*)(out + (size_t)c * 65536 + rowbase + nl * 4) = s;
    }
}

extern "C" void kernel_launch(void* const* d_in, const int* in_sizes, int n_in,
                              void* d_out, int out_size, void* d_ws, size_t ws_size,
                              hipStream_t stream) {
    const float* query = (const float*)d_in[0];
    const float* key   = (const float*)d_in[1];
    const float* value = (const float*)d_in[2];
    const float* Wq = (const float*)d_in[3];
    const float* bq = (const float*)d_in[4];
    const float* Wk = (const float*)d_in[5];
    const float* bk = (const float*)d_in[6];
    const float* Wv = (const float*)d_in[7];
    const float* bv = (const float*)d_in[8];
    float* out = (float*)d_out;
    float* ws  = (float*)d_ws;
    float* scratch = out;  // partials region (256*16896 floats < 8388608), overwritten by kernelC

    hipLaunchKernelGGL(kernelA, dim3(256), dim3(256), 0, stream, key, value, scratch);
    hipLaunchKernelGGL(kernelR, dim3(260), dim3(256), 0, stream, scratch, ws);
    hipLaunchKernelGGL(kernelB, dim3(4), dim3(256), 0, stream, Wk, bk, Wv, bv, Wq, bq, ws, out);
    hipLaunchKernelGGL(kernelC, dim3(512), dim3(512), 0, stream, query, ws, out);
}

// Round 5
// 197.375 us; speedup vs baseline: 2.9838x; 1.1627x over previous
//
#include <hip/hip_runtime.h>

typedef __attribute__((ext_vector_type(8))) short short8;
typedef __attribute__((ext_vector_type(4))) float f32x4;

// ws layout (floats)
#define WS_CKV  0        // 128*128 fp32 Gram (written by kernelR)
#define WS_SKEY 16384    // 128 col sums of key
#define WS_SVAL 16512    // 128 col sums of value
#define WS_W2T  16640    // ushort[128*128] bf16 W2 transposed [c][k]
#define WS_B2   24832    // 128 fp32 bias

// scratch inside d_out (overwritten by kernelC):
//   bf16 partial tiles: ushort[512][16384]  = float offsets [0, 4194304)
//   fp32 colsum partials: floats [4194304, 4194304 + 512*256)
#define SCR_CS  4194304

__device__ inline ushort f2bf(float f) {
    uint u = __float_as_uint(f);
    return (ushort)((u + 0x7FFFu + ((u >> 16) & 1u)) >> 16);   // RNE
}
__device__ inline uint pack_bf16(float a, float b) {
    return (uint)f2bf(a) | ((uint)f2bf(b) << 16);
}
__device__ inline float bf2f(ushort u) { return __uint_as_float(((uint)u) << 16); }

// ---------------------------------------------------------------------------
// Kernel A: per-block partial C = key_blk^T @ value_blk (fp32 acc) + colsums.
// 512 blocks x 512 thr, 128 rows/block, dbuf 32-row tiles. 2 blocks/CU ->
// 4 waves/SIMD. Partial tile stored bf16, colsums fp32, both into out-scratch.
// ---------------------------------------------------------------------------
__global__ __launch_bounds__(512, 4) void kernelA(const float* __restrict__ key,
                                                  const float* __restrict__ value,
                                                  float* __restrict__ outbuf) {
    __shared__ float lk[2][32 * 128];
    __shared__ float lv[2][32 * 128];
    __shared__ float red[256];

    const int tid = threadIdx.x;
    const int i0 = (tid >> 5) * 8;   // 0..120
    const int j0 = (tid & 31) * 4;   // 0..124
    const int row0 = blockIdx.x * 128;

    const float4* __restrict__ k4 = (const float4*)key;
    const float4* __restrict__ v4 = (const float4*)value;

    float acc[8][4];
#pragma unroll
    for (int a = 0; a < 8; ++a)
#pragma unroll
        for (int b = 0; b < 4; ++b) acc[a][b] = 0.f;

    float sk[4] = {0.f, 0.f, 0.f, 0.f};
    float sv[4] = {0.f, 0.f, 0.f, 0.f};

    float4 rk[2], rv[2];
    {   // prologue tile 0
        const int g = row0 * 32;
        rk[0] = k4[g + tid]; rk[1] = k4[g + tid + 512];
        rv[0] = v4[g + tid]; rv[1] = v4[g + tid + 512];
        ((float4*)lk[0])[tid] = rk[0]; ((float4*)lk[0])[tid + 512] = rk[1];
        ((float4*)lv[0])[tid] = rv[0]; ((float4*)lv[0])[tid + 512] = rv[1];
#pragma unroll
        for (int q = 0; q < 2; ++q) {
            sk[0] += rk[q].x; sk[1] += rk[q].y; sk[2] += rk[q].z; sk[3] += rk[q].w;
            sv[0] += rv[q].x; sv[1] += rv[q].y; sv[2] += rv[q].z; sv[3] += rv[q].w;
        }
    }
    __syncthreads();

    for (int t = 0; t < 4; ++t) {
        const int cur = t & 1;
        if (t < 3) {
            const int g = (row0 + (t + 1) * 32) * 32;
            rk[0] = k4[g + tid]; rk[1] = k4[g + tid + 512];
            rv[0] = v4[g + tid]; rv[1] = v4[g + tid + 512];
        }
#pragma unroll 4
        for (int kk = 0; kk < 32; ++kk) {
            float ka[8], vb[4];
            *(float4*)&ka[0] = *(const float4*)&lk[cur][kk * 128 + i0];
            *(float4*)&ka[4] = *(const float4*)&lk[cur][kk * 128 + i0 + 4];
            *(float4*)&vb[0] = *(const float4*)&lv[cur][kk * 128 + j0];
#pragma unroll
            for (int a = 0; a < 8; ++a)
#pragma unroll
                for (int b = 0; b < 4; ++b)
                    acc[a][b] = fmaf(ka[a], vb[b], acc[a][b]);
        }
        if (t < 3) {
            const int nxt = cur ^ 1;
            ((float4*)lk[nxt])[tid] = rk[0]; ((float4*)lk[nxt])[tid + 512] = rk[1];
            ((float4*)lv[nxt])[tid] = rv[0]; ((float4*)lv[nxt])[tid + 512] = rv[1];
#pragma unroll
            for (int q = 0; q < 2; ++q) {
                sk[0] += rk[q].x; sk[1] += rk[q].y; sk[2] += rk[q].z; sk[3] += rk[q].w;
                sv[0] += rv[q].x; sv[1] += rv[q].y; sv[2] += rv[q].z; sv[3] += rv[q].w;
            }
            __syncthreads();
        }
    }

    // colsum LDS reduce
    if (tid < 256) red[tid] = 0.f;
    __syncthreads();
    const int cg = (tid & 31) * 4;
#pragma unroll
    for (int a = 0; a < 4; ++a) {
        atomicAdd(&red[cg + a], sk[a]);
        atomicAdd(&red[128 + cg + a], sv[a]);
    }
    __syncthreads();

    // store partial tile (bf16) + colsums (fp32)
    ushort* __restrict__ tile = (ushort*)outbuf + (size_t)blockIdx.x * 16384;
#pragma unroll
    for (int a = 0; a < 8; ++a) {
        uint2 s;
        s.x = pack_bf16(acc[a][0], acc[a][1]);
        s.y = pack_bf16(acc[a][2], acc[a][3]);
        *(uint2*)&tile[(i0 + a) * 128 + j0] = s;
    }
    if (tid < 256) outbuf[SCR_CS + blockIdx.x * 256 + tid] = red[tid];
}

// ---------------------------------------------------------------------------
// Kernel R: reduce 512 partials. Blocks 0..255: Gram tile (bf16 -> fp32 sum);
// blocks 256..259: colsums (fp32). 512 thr, 8 partial-groups x 8 chains.
// ---------------------------------------------------------------------------
__global__ __launch_bounds__(512) void kernelR(const float* __restrict__ outbuf,
                                               float* __restrict__ ws) {
    __shared__ float red[8][64];
    const int tid = threadIdx.x;
    const int b = blockIdx.x;
    const int lane = tid & 63;
    const int g = tid >> 6;   // 0..7
    const int p0 = g * 64;

    float s[8];
#pragma unroll
    for (int c = 0; c < 8; ++c) s[c] = 0.f;

    if (b < 256) {
        const ushort* __restrict__ tile = (const ushort*)outbuf;
        const int e = b * 64 + lane;
        for (int r = 0; r < 8; ++r) {
#pragma unroll
            for (int c = 0; c < 8; ++c)
                s[c] += bf2f(tile[(size_t)(p0 + c * 8 + r) * 16384 + e]);
        }
    } else {
        const int e = (b - 256) * 64 + lane;   // 0..255
        for (int r = 0; r < 8; ++r) {
#pragma unroll
            for (int c = 0; c < 8; ++c)
                s[c] += outbuf[SCR_CS + (p0 + c * 8 + r) * 256 + e];
        }
    }
    red[g][lane] = ((s[0] + s[1]) + (s[2] + s[3])) + ((s[4] + s[5]) + (s[6] + s[7]));
    __syncthreads();
    if (tid < 64) {
        float r = ((red[0][lane] + red[1][lane]) + (red[2][lane] + red[3][lane])) +
                  ((red[4][lane] + red[5][lane]) + (red[6][lane] + red[7][lane]));
        if (b < 256) ws[b * 64 + lane] = r;
        else ws[WS_SKEY + (b - 256) * 64 + lane] = r;   // skey then sval
    }
}

// ---------------------------------------------------------------------------
// Kernel B: per-head (4 blocks x 512 thr): T = C Wv_h^T; p; W2 (bf16 [c][k]);
// b2. Writes p_attn (fp32) to out tail. Padded LDS rows (stride 132) to
// spread banks.
// ---------------------------------------------------------------------------
__global__ __launch_bounds__(512) void kernelB(const float* __restrict__ Wk, const float* __restrict__ bk,
                                               const float* __restrict__ Wv, const float* __restrict__ bv,
                                               const float* __restrict__ Wq, const float* __restrict__ bq,
                                               float* __restrict__ ws, float* __restrict__ out) {
    __shared__ float ckv[128 * 132];
    __shared__ float wvT[128 * 32];   // [j][e]
    __shared__ float wk_s[32 * 132];  // [d][i]
    __shared__ float wq_s[32 * 132];  // [d][k]
    __shared__ float Tl[128 * 32];    // [i][e]
    __shared__ float pl[32 * 32];     // [d][e]
    __shared__ float skey[128], sval[128];
    __shared__ float bk_s[32], bv_s[32], bq_s[32];
    __shared__ float wvec[32], uvec[32];

    const int tid = threadIdx.x;
    const int h = blockIdx.x;

    const float4* __restrict__ ws4 = (const float4*)ws;
    const float4* __restrict__ Wk4 = (const float4*)Wk;
    const float4* __restrict__ Wq4 = (const float4*)Wq;
    const float4* __restrict__ Wv4 = (const float4*)Wv;

#pragma unroll
    for (int q = 0; q < 8; ++q) {
        const int idx = tid + 512 * q;           // 0..4095
        float4 v = ws4[(WS_CKV >> 2) + idx];
        *(float4*)&ckv[(idx >> 5) * 132 + (idx & 31) * 4] = v;
    }
#pragma unroll
    for (int q = 0; q < 2; ++q) {
        const int idx = tid + 512 * q;           // 0..1023
        float4 a = Wk4[h * 1024 + idx];
        float4 b = Wq4[h * 1024 + idx];
        *(float4*)&wk_s[(idx >> 5) * 132 + (idx & 31) * 4] = a;
        *(float4*)&wq_s[(idx >> 5) * 132 + (idx & 31) * 4] = b;
    }
#pragma unroll
    for (int q = 0; q < 2; ++q) {
        const int f = tid + 512 * q;
        const int e = f >> 5;
        const int c = (f & 31) * 4;
        float4 v = Wv4[h * 1024 + f];
        wvT[(c + 0) * 32 + e] = v.x;
        wvT[(c + 1) * 32 + e] = v.y;
        wvT[(c + 2) * 32 + e] = v.z;
        wvT[(c + 3) * 32 + e] = v.w;
    }
    if (tid < 128) { skey[tid] = ws[WS_SKEY + tid]; sval[tid] = ws[WS_SVAL + tid]; }
    else if (tid >= 256 && tid < 288) {
        const int u = tid - 256;
        bk_s[u] = bk[h * 32 + u]; bv_s[u] = bv[h * 32 + u]; bq_s[u] = bq[h * 32 + u];
    }
    __syncthreads();

    // T[i][e] = sum_j ckv[i][j] * wvT[j][e]
    {
        const int i = tid >> 2;
        const int e0 = (tid & 3) * 8;
        float accT8[8];
#pragma unroll
        for (int e = 0; e < 8; ++e) accT8[e] = 0.f;
        for (int j = 0; j < 128; ++j) {
            const float cv = ckv[i * 132 + j];
            const float* wr = &wvT[j * 32 + e0];
#pragma unroll
            for (int e = 0; e < 8; ++e) accT8[e] = fmaf(cv, wr[e], accT8[e]);
        }
#pragma unroll
        for (int e = 0; e < 8; e += 4)
            *(float4*)&Tl[i * 32 + e0 + e] = make_float4(accT8[e], accT8[e+1], accT8[e+2], accT8[e+3]);

        if (tid < 32) {
            float u = 0.f;
            for (int j = 0; j < 128; ++j) u = fmaf(wvT[j * 32 + tid], sval[j], u);
            uvec[tid] = u;
        } else if (tid < 64) {
            const int a = tid - 32;
            float w = 0.f;
            for (int i2 = 0; i2 < 128; ++i2) w = fmaf(wk_s[a * 132 + i2], skey[i2], w);
            wvec[a] = w;
        }
    }
    __syncthreads();

    // p[d][e], 2 per thread
    {
        const int d = tid >> 4;           // 0..31
        const int e2 = (tid & 15) * 2;    // 0..30
        float pa = 0.f, pb = 0.f;
        for (int i2 = 0; i2 < 128; ++i2) {
            const float wkv = wk_s[d * 132 + i2];
            pa = fmaf(wkv, Tl[i2 * 32 + e2], pa);
            pb = fmaf(wkv, Tl[i2 * 32 + e2 + 1], pb);
        }
        const float p0 = (pa + wvec[d] * bv_s[e2] + bk_s[d] * uvec[e2] +
                          65536.f * bk_s[d] * bv_s[e2]) * (1.f / 65536.f);
        const float p1 = (pb + wvec[d] * bv_s[e2 + 1] + bk_s[d] * uvec[e2 + 1] +
                          65536.f * bk_s[d] * bv_s[e2 + 1]) * (1.f / 65536.f);
        pl[d * 32 + e2] = p0; pl[d * 32 + e2 + 1] = p1;
        *(float2*)&out[8388608 + h * 1024 + d * 32 + e2] = make_float2(p0, p1);
    }
    __syncthreads();

    // W2T bf16 [c][k]: W2[k][c] = sum_d wq_s[d][k] * pl[d][c-h*32]
    {
        const int k = tid >> 2;
        const int e0 = (tid & 3) * 8;
        float accW[8];
#pragma unroll
        for (int e = 0; e < 8; ++e) accW[e] = 0.f;
        for (int d = 0; d < 32; ++d) {
            const float wq = wq_s[d * 132 + k];
            const float* pr = &pl[d * 32 + e0];
#pragma unroll
            for (int e = 0; e < 8; ++e) accW[e] = fmaf(wq, pr[e], accW[e]);
        }
        ushort* __restrict__ w2t = (ushort*)(ws + WS_W2T);
#pragma unroll
        for (int e = 0; e < 8; ++e)
            w2t[(h * 32 + e0 + e) * 128 + k] = f2bf(accW[e]);

        if (tid < 32) {
            float b2v = 0.f;
#pragma unroll
            for (int d = 0; d < 32; ++d) b2v = fmaf(bq_s[d], pl[d * 32 + tid], b2v);
            ws[WS_B2 + h * 32 + tid] = b2v;
        }
    }
}

// ---------------------------------------------------------------------------
// Kernel C: x = query @ W2 + b2 via bf16 MFMA, stored transposed
// out[c*65536 + n]. 512 blocks x 256 thr (4 waves, 2x2), 128 rows x 128 cols
// per block. LDS-transpose epilogue -> full-line column stores.
// ---------------------------------------------------------------------------
__global__ __launch_bounds__(256, 2) void kernelC(const float* __restrict__ query,
                                                  const float* __restrict__ ws,
                                                  float* __restrict__ out) {
    __shared__ __align__(16) ushort qs[128 * 136];   // bf16 [r][k]; epilogue: fp32 tmp[32][132]
    __shared__ __align__(16) ushort w2s[128 * 136];  // bf16 [c][k]
    __shared__ float b2s[128];

    const int tid = threadIdx.x;
    const int lane = tid & 63;
    const int w = tid >> 6;
    const int wr = w >> 1, wc = w & 1;
    const int rowbase = blockIdx.x * 128;

    // stage query -> bf16 qs
    {
        const float4* __restrict__ q4 = (const float4*)query;
        const int r = tid >> 1, half = tid & 1;
        const int gbase = (rowbase + r) * 32 + half * 16;
#pragma unroll
        for (int m = 0; m < 8; ++m) {
            float4 f0 = q4[gbase + m * 2], f1 = q4[gbase + m * 2 + 1];
            uint4 pk;
            pk.x = pack_bf16(f0.x, f0.y); pk.y = pack_bf16(f0.z, f0.w);
            pk.z = pack_bf16(f1.x, f1.y); pk.w = pack_bf16(f1.z, f1.w);
            *(uint4*)&qs[r * 136 + half * 64 + m * 8] = pk;
        }
    }
    // stage W2T -> w2s
    {
        const uint4* __restrict__ wsrc = (const uint4*)((const ushort*)(ws + WS_W2T));
        const int c = tid >> 1, half = tid & 1;
#pragma unroll
        for (int m = 0; m < 8; ++m) {
            uint4 v = wsrc[c * 16 + half * 8 + m];
            *(uint4*)&w2s[c * 136 + half * 64 + m * 8] = v;
        }
    }
    if (tid < 32) ((float4*)b2s)[tid] = ((const float4*)(ws + WS_B2))[tid];
    __syncthreads();

    // preload all B-frags (W2 for this wave's 64 cols)
    short8 bfrag[4][4];
#pragma unroll
    for (int ct = 0; ct < 4; ++ct)
#pragma unroll
        for (int ks = 0; ks < 4; ++ks)
            bfrag[ct][ks] = *(const short8*)&w2s[(wc * 64 + ct * 16 + (lane & 15)) * 136 + ks * 32 + (lane >> 4) * 8];

    f32x4 acc[4][4];
#pragma unroll
    for (int rt = 0; rt < 4; ++rt)
#pragma unroll
        for (int ct = 0; ct < 4; ++ct) acc[rt][ct] = (f32x4){0.f, 0.f, 0.f, 0.f};

#pragma unroll
    for (int ks = 0; ks < 4; ++ks) {
        short8 af[4];
#pragma unroll
        for (int rt = 0; rt < 4; ++rt)
            af[rt] = *(const short8*)&qs[(wr * 64 + rt * 16 + (lane & 15)) * 136 + ks * 32 + (lane >> 4) * 8];
#pragma unroll
        for (int rt = 0; rt < 4; ++rt)
#pragma unroll
            for (int ct = 0; ct < 4; ++ct)
                acc[rt][ct] = __builtin_amdgcn_mfma_f32_16x16x32_bf16(af[rt], bfrag[ct][ks], acc[rt][ct], 0, 0, 0);
    }
    __syncthreads();

    // epilogue: 4 passes of 32 cols via LDS transpose (reuse qs as fp32 tmp)
    float* tmp = (float*)qs;   // [32][132]
#pragma unroll
    for (int cp = 0; cp < 4; ++cp) {
        if (wc == (cp >> 1)) {
#pragma unroll
            for (int rt = 0; rt < 4; ++rt)
#pragma unroll
                for (int tc = 0; tc < 2; ++tc) {
                    const int ct = (cp & 1) * 2 + tc;
                    const int cl = tc * 16 + (lane & 15);
                    const int r = wr * 64 + rt * 16 + (lane >> 4) * 4;
                    *(f32x4*)&tmp[cl * 132 + r] = acc[rt][ct];
                }
        }
        __syncthreads();
        {
            const int cl = tid >> 3;             // 0..31
            const int c = cp * 32 + cl;
            const float bb = b2s[c];
            float* __restrict__ col = out + (size_t)c * 65536 + rowbase;
#pragma unroll
            for (int ch = 0; ch < 4; ++ch) {
                const int r4 = (tid & 7) + ch * 8;   // 0..31
                float4 v = *(const float4*)&tmp[cl * 132 + r4 * 4];
                v.x += bb; v.y += bb; v.z += bb; v.w += bb;
                *(float4*)&col[r4 * 4] = v;
            }
        }
        __syncthreads();
    }
}

extern "C" void kernel_launch(void* const* d_in, const int* in_sizes, int n_in,
                              void* d_out, int out_size, void* d_ws, size_t ws_size,
                              hipStream_t stream) {
    const float* query = (const float*)d_in[0];
    const float* key   = (const float*)d_in[1];
    const float* value = (const float*)d_in[2];
    const float* Wq = (const float*)d_in[3];
    const float* bq = (const float*)d_in[4];
    const float* Wk = (const float*)d_in[5];
    const float* bk = (const float*)d_in[6];
    const float* Wv = (const float*)d_in[7];
    const float* bv = (const float*)d_in[8];
    float* out = (float*)d_out;
    float* ws  = (float*)d_ws;

    hipLaunchKernelGGL(kernelA, dim3(512), dim3(512), 0, stream, key, value, out);
    hipLaunchKernelGGL(kernelR, dim3(260), dim3(512), 0, stream, out, ws);
    hipLaunchKernelGGL(kernelB, dim3(4), dim3(512), 0, stream, Wk, bk, Wv, bv, Wq, bq, ws, out);
    hipLaunchKernelGGL(kernelC, dim3(512), dim3(256), 0, stream, query, ws, out);
}

// Round 8
// 178.701 us; speedup vs baseline: 3.2956x; 1.1045x over previous
//
#include <hip/hip_runtime.h>

typedef __attribute__((ext_vector_type(8))) short short8;
typedef __attribute__((ext_vector_type(4))) float f32x4;

// ws layout (floats)
#define WS_CKV  0        // 128*128 fp32 Gram (written by kernelR)
#define WS_SKEY 16384    // 128 col sums of key
#define WS_SVAL 16512    // 128 col sums of value
#define WS_W2T  16640    // ushort[128*128] bf16 W2 transposed [c][k]
#define WS_B2   24832    // 128 fp32 bias

// scratch inside d_out (overwritten by kernelC):
//   bf16 partial tiles: ushort[512][16384]  = float offsets [0, 4194304)
//   fp32 colsum partials: floats [4194304, 4194304 + 512*256)
#define SCR_CS  4194304

__device__ inline ushort f2bf(float f) {
    uint u = __float_as_uint(f);
    return (ushort)((u + 0x7FFFu + ((u >> 16) & 1u)) >> 16);   // RNE
}
__device__ inline uint pack_bf16(float a, float b) {
    return (uint)f2bf(a) | ((uint)f2bf(b) << 16);
}
__device__ inline float bf2f(ushort u) { return __uint_as_float(((uint)u) << 16); }

// ---------------------------------------------------------------------------
// Kernel A: partial C = key_blk^T @ value_blk via bf16 MFMA (fp32 acc) +
// fp32 colsums. 512 blocks x 512 thr (8 waves), 128 rows/block, 4 dbuf chunks
// of 32 rows. LDS tiles [i][n] bf16, row stride 40 ushorts (20 dwords).
// GROUP-level XOR swizzle: n-pair dword position = n2 ^ (((i>>3)&3) << 2) --
// swizzles 16B groups so the b128 fragment read at group g^s is 4 contiguous
// dwords with ascending-n order (identical k-order for A and B operands).
// Wave w owns 16-row strip; 8 col-tiles of 16x16x32 mfma. Partial tile
// restaged through LDS -> coalesced bf16 stores.
// ---------------------------------------------------------------------------
__global__ __launch_bounds__(512, 4) void kernelA(const float* __restrict__ key,
                                                  const float* __restrict__ value,
                                                  float* __restrict__ outbuf) {
    __shared__ __align__(16) ushort sm[4][128 * 40];  // [buf*2+arr][i*40 + n]
    __shared__ float red[256];

    const int tid = threadIdx.x;
    const int l = tid & 63;
    const int w = tid >> 6;            // wave 0..7
    const int rs = w * 16;             // row strip
    const int row0 = blockIdx.x * 128;

    const float4* __restrict__ k4 = (const float4*)key;
    const float4* __restrict__ v4 = (const float4*)value;

    // staging coords: thread loads rows (2*n2, 2*n2+1) at float4-col i4
    const int n2 = tid >> 5;           // n-pair 0..15
    const int i4 = tid & 31;
    const int i0 = i4 * 4;
    // group-level swizzle: s = (i>>3)&3 = (i4>>1)&3 for rows i0..i0+3
    const int nds = n2 ^ (((i4 >> 1) & 3) << 2);

    // mfma coords
    const int lr = l & 15;
    const int g = l >> 4;              // k-group 0..3

    f32x4 acc[8];
#pragma unroll
    for (int c = 0; c < 8; ++c) acc[c] = (f32x4){0.f, 0.f, 0.f, 0.f};

    float sk[4] = {0.f, 0.f, 0.f, 0.f};
    float sv[4] = {0.f, 0.f, 0.f, 0.f};

    float4 rka, rkb, rva, rvb;
    {   // prologue: chunk 0
        const int gb = (row0 + 2 * n2) * 32 + i4;
        rka = k4[gb]; rkb = k4[gb + 32];
        rva = v4[gb]; rvb = v4[gb + 32];
        uint* dk = (uint*)sm[0];
        uint* dv = (uint*)sm[1];
        const float* pa = (const float*)&rka; const float* pb = (const float*)&rkb;
        const float* pc = (const float*)&rva; const float* pd = (const float*)&rvb;
#pragma unroll
        for (int q = 0; q < 4; ++q) {
            dk[(i0 + q) * 20 + nds] = pack_bf16(pa[q], pb[q]);
            dv[(i0 + q) * 20 + nds] = pack_bf16(pc[q], pd[q]);
            sk[q] += pa[q] + pb[q];
            sv[q] += pc[q] + pd[q];
        }
    }
    __syncthreads();

    for (int t = 0; t < 4; ++t) {
        const int cur = t & 1;
        if (t < 3) {   // prefetch next chunk
            const int gb = (row0 + (t + 1) * 32 + 2 * n2) * 32 + i4;
            rka = k4[gb]; rkb = k4[gb + 32];
            rva = v4[gb]; rvb = v4[gb + 32];
        }
        {   // mfma on chunk cur
            const ushort* sK = sm[cur * 2 + 0];
            const ushort* sV = sm[cur * 2 + 1];
            const int ia = rs + lr;
            const int ga = g ^ ((ia >> 3) & 3);
            short8 af = *(const short8*)(sK + ia * 40 + ga * 8);
#pragma unroll
            for (int c = 0; c < 8; ++c) {
                const int ib = c * 16 + lr;
                const int gb2 = g ^ ((ib >> 3) & 3);
                short8 bf = *(const short8*)(sV + ib * 40 + gb2 * 8);
                acc[c] = __builtin_amdgcn_mfma_f32_16x16x32_bf16(af, bf, acc[c], 0, 0, 0);
            }
        }
        if (t < 3) {
            const int nxt = cur ^ 1;
            uint* dk = (uint*)sm[nxt * 2 + 0];
            uint* dv = (uint*)sm[nxt * 2 + 1];
            const float* pa = (const float*)&rka; const float* pb = (const float*)&rkb;
            const float* pc = (const float*)&rva; const float* pd = (const float*)&rvb;
#pragma unroll
            for (int q = 0; q < 4; ++q) {
                dk[(i0 + q) * 20 + nds] = pack_bf16(pa[q], pb[q]);
                dv[(i0 + q) * 20 + nds] = pack_bf16(pc[q], pd[q]);
                sk[q] += pa[q] + pb[q];
                sv[q] += pc[q] + pd[q];
            }
            __syncthreads();
        }
    }

    // colsum reduce setup; sync also guards LDS reuse after last mfma
    if (tid < 256) red[tid] = 0.f;
    __syncthreads();
#pragma unroll
    for (int q = 0; q < 4; ++q) {
        atomicAdd(&red[i0 + q], sk[q]);
        atomicAdd(&red[128 + i0 + q], sv[q]);
    }

    // restage C tile (bf16) through LDS: sc[128][136]
    ushort* sc = sm[0];
#pragma unroll
    for (int c = 0; c < 8; ++c) {
        const float* av = (const float*)&acc[c];
#pragma unroll
        for (int r = 0; r < 4; ++r)
            sc[(rs + g * 4 + r) * 136 + c * 16 + lr] = f2bf(av[r]);
    }
    __syncthreads();

    ushort* __restrict__ tile = (ushort*)outbuf + (size_t)blockIdx.x * 16384;
#pragma unroll
    for (int q2 = 0; q2 < 4; ++q2) {
        const int id = tid + 512 * q2;        // 0..2047
        const int r = id >> 4, p = id & 15;
        ((uint4*)tile)[id] = *(const uint4*)(sc + r * 136 + p * 8);
    }
    if (tid < 256) outbuf[SCR_CS + blockIdx.x * 256 + tid] = red[tid];
}

// ---------------------------------------------------------------------------
// Kernel R: reduce 512 partials. Blocks 0..255: Gram tile (bf16 -> fp32 sum);
// blocks 256..259: colsums (fp32). 512 thr, 8 partial-groups x 8 chains.
// ---------------------------------------------------------------------------
__global__ __launch_bounds__(512) void kernelR(const float* __restrict__ outbuf,
                                               float* __restrict__ ws) {
    __shared__ float red[8][64];
    const int tid = threadIdx.x;
    const int b = blockIdx.x;
    const int lane = tid & 63;
    const int g = tid >> 6;   // 0..7
    const int p0 = g * 64;

    float s[8];
#pragma unroll
    for (int c = 0; c < 8; ++c) s[c] = 0.f;

    if (b < 256) {
        const ushort* __restrict__ tile = (const ushort*)outbuf;
        const int e = b * 64 + lane;
        for (int r = 0; r < 8; ++r) {
#pragma unroll
            for (int c = 0; c < 8; ++c)
                s[c] += bf2f(tile[(size_t)(p0 + c * 8 + r) * 16384 + e]);
        }
    } else {
        const int e = (b - 256) * 64 + lane;   // 0..255
        for (int r = 0; r < 8; ++r) {
#pragma unroll
            for (int c = 0; c < 8; ++c)
                s[c] += outbuf[SCR_CS + (p0 + c * 8 + r) * 256 + e];
        }
    }
    red[g][lane] = ((s[0] + s[1]) + (s[2] + s[3])) + ((s[4] + s[5]) + (s[6] + s[7]));
    __syncthreads();
    if (tid < 64) {
        float r = ((red[0][lane] + red[1][lane]) + (red[2][lane] + red[3][lane])) +
                  ((red[4][lane] + red[5][lane]) + (red[6][lane] + red[7][lane]));
        if (b < 256) ws[b * 64 + lane] = r;
        else ws[WS_SKEY + (b - 256) * 64 + lane] = r;   // skey then sval
    }
}

// ---------------------------------------------------------------------------
// Kernel B: per-head (4 blocks x 512 thr): T = C Wv_h^T; p; W2 (bf16 [c][k]);
// b2. Writes p_attn (fp32) to out tail. Padded LDS rows (stride 132).
// ---------------------------------------------------------------------------
__global__ __launch_bounds__(512) void kernelB(const float* __restrict__ Wk, const float* __restrict__ bk,
                                               const float* __restrict__ Wv, const float* __restrict__ bv,
                                               const float* __restrict__ Wq, const float* __restrict__ bq,
                                               float* __restrict__ ws, float* __restrict__ out) {
    __shared__ float ckv[128 * 132];
    __shared__ float wvT[128 * 32];   // [j][e]
    __shared__ float wk_s[32 * 132];  // [d][i]
    __shared__ float wq_s[32 * 132];  // [d][k]
    __shared__ float Tl[128 * 32];    // [i][e]
    __shared__ float pl[32 * 32];     // [d][e]
    __shared__ float skey[128], sval[128];
    __shared__ float bk_s[32], bv_s[32], bq_s[32];
    __shared__ float wvec[32], uvec[32];

    const int tid = threadIdx.x;
    const int h = blockIdx.x;

    const float4* __restrict__ ws4 = (const float4*)ws;
    const float4* __restrict__ Wk4 = (const float4*)Wk;
    const float4* __restrict__ Wq4 = (const float4*)Wq;
    const float4* __restrict__ Wv4 = (const float4*)Wv;

#pragma unroll
    for (int q = 0; q < 8; ++q) {
        const int idx = tid + 512 * q;           // 0..4095
        float4 v = ws4[(WS_CKV >> 2) + idx];
        *(float4*)&ckv[(idx >> 5) * 132 + (idx & 31) * 4] = v;
    }
#pragma unroll
    for (int q = 0; q < 2; ++q) {
        const int idx = tid + 512 * q;           // 0..1023
        float4 a = Wk4[h * 1024 + idx];
        float4 b = Wq4[h * 1024 + idx];
        *(float4*)&wk_s[(idx >> 5) * 132 + (idx & 31) * 4] = a;
        *(float4*)&wq_s[(idx >> 5) * 132 + (idx & 31) * 4] = b;
    }
#pragma unroll
    for (int q = 0; q < 2; ++q) {
        const int f = tid + 512 * q;
        const int e = f >> 5;
        const int c = (f & 31) * 4;
        float4 v = Wv4[h * 1024 + f];
        wvT[(c + 0) * 32 + e] = v.x;
        wvT[(c + 1) * 32 + e] = v.y;
        wvT[(c + 2) * 32 + e] = v.z;
        wvT[(c + 3) * 32 + e] = v.w;
    }
    if (tid < 128) { skey[tid] = ws[WS_SKEY + tid]; sval[tid] = ws[WS_SVAL + tid]; }
    else if (tid >= 256 && tid < 288) {
        const int u = tid - 256;
        bk_s[u] = bk[h * 32 + u]; bv_s[u] = bv[h * 32 + u]; bq_s[u] = bq[h * 32 + u];
    }
    __syncthreads();

    // T[i][e] = sum_j ckv[i][j] * wvT[j][e]
    {
        const int i = tid >> 2;
        const int e0 = (tid & 3) * 8;
        float accT8[8];
#pragma unroll
        for (int e = 0; e < 8; ++e) accT8[e] = 0.f;
        for (int j = 0; j < 128; ++j) {
            const float cv = ckv[i * 132 + j];
            const float* wr = &wvT[j * 32 + e0];
#pragma unroll
            for (int e = 0; e < 8; ++e) accT8[e] = fmaf(cv, wr[e], accT8[e]);
        }
#pragma unroll
        for (int e = 0; e < 8; e += 4)
            *(float4*)&Tl[i * 32 + e0 + e] = make_float4(accT8[e], accT8[e+1], accT8[e+2], accT8[e+3]);

        if (tid < 32) {
            float u = 0.f;
            for (int j = 0; j < 128; ++j) u = fmaf(wvT[j * 32 + tid], sval[j], u);
            uvec[tid] = u;
        } else if (tid < 64) {
            const int a = tid - 32;
            float w = 0.f;
            for (int i2 = 0; i2 < 128; ++i2) w = fmaf(wk_s[a * 132 + i2], skey[i2], w);
            wvec[a] = w;
        }
    }
    __syncthreads();

    // p[d][e], 2 per thread
    {
        const int d = tid >> 4;           // 0..31
        const int e2 = (tid & 15) * 2;    // 0..30
        float pa = 0.f, pb = 0.f;
        for (int i2 = 0; i2 < 128; ++i2) {
            const float wkv = wk_s[d * 132 + i2];
            pa = fmaf(wkv, Tl[i2 * 32 + e2], pa);
            pb = fmaf(wkv, Tl[i2 * 32 + e2 + 1], pb);
        }
        const float p0 = (pa + wvec[d] * bv_s[e2] + bk_s[d] * uvec[e2] +
                          65536.f * bk_s[d] * bv_s[e2]) * (1.f / 65536.f);
        const float p1 = (pb + wvec[d] * bv_s[e2 + 1] + bk_s[d] * uvec[e2 + 1] +
                          65536.f * bk_s[d] * bv_s[e2 + 1]) * (1.f / 65536.f);
        pl[d * 32 + e2] = p0; pl[d * 32 + e2 + 1] = p1;
        *(float2*)&out[8388608 + h * 1024 + d * 32 + e2] = make_float2(p0, p1);
    }
    __syncthreads();

    // W2T bf16 [c][k]: W2[k][c] = sum_d wq_s[d][k] * pl[d][c-h*32]
    {
        const int k = tid >> 2;
        const int e0 = (tid & 3) * 8;
        float accW[8];
#pragma unroll
        for (int e = 0; e < 8; ++e) accW[e] = 0.f;
        for (int d = 0; d < 32; ++d) {
            const float wq = wq_s[d * 132 + k];
            const float* pr = &pl[d * 32 + e0];
#pragma unroll
            for (int e = 0; e < 8; ++e) accW[e] = fmaf(wq, pr[e], accW[e]);
        }
        ushort* __restrict__ w2t = (ushort*)(ws + WS_W2T);
#pragma unroll
        for (int e = 0; e < 8; ++e)
            w2t[(h * 32 + e0 + e) * 128 + k] = f2bf(accW[e]);

        if (tid < 32) {
            float b2v = 0.f;
#pragma unroll
            for (int d = 0; d < 32; ++d) b2v = fmaf(bq_s[d], pl[d * 32 + tid], b2v);
            ws[WS_B2 + h * 32 + tid] = b2v;
        }
    }
}

// ---------------------------------------------------------------------------
// Kernel C: x = query @ W2 + b2 via bf16 MFMA, stored transposed
// out[c*65536 + n]. 512 blocks x 256 thr (4 waves, 2x2), 128 rows x 128 cols
// per block. Linear-coalesced staging; LDS-transpose epilogue -> full-line
// column stores.
// ---------------------------------------------------------------------------
__global__ __launch_bounds__(256, 2) void kernelC(const float* __restrict__ query,
                                                  const float* __restrict__ ws,
                                                  float* __restrict__ out) {
    __shared__ __align__(16) ushort qs[128 * 136];   // bf16 [r][k]; epilogue: fp32 tmp[32][132]
    __shared__ __align__(16) ushort w2s[128 * 136];  // bf16 [c][k]
    __shared__ float b2s[128];

    const int tid = threadIdx.x;
    const int lane = tid & 63;
    const int w = tid >> 6;
    const int wr = w >> 1, wc = w & 1;
    const int rowbase = blockIdx.x * 128;

    // stage query -> bf16 qs, fully linear-coalesced global reads
    {
        const float4* __restrict__ q4 = (const float4*)query + (size_t)rowbase * 32;
        uint2* __restrict__ qd = (uint2*)qs;
#pragma unroll
        for (int it = 0; it < 16; ++it) {
            const int idx = tid + 256 * it;       // 0..4095
            float4 f = q4[idx];
            const int r = idx >> 5, c4 = idx & 31;
            uint2 pk;
            pk.x = pack_bf16(f.x, f.y);
            pk.y = pack_bf16(f.z, f.w);
            qd[r * 34 + c4] = pk;
        }
    }
    // stage W2T -> w2s, linear
    {
        const uint4* __restrict__ wsrc = (const uint4*)((const ushort*)(ws + WS_W2T));
        uint4* __restrict__ wd = (uint4*)w2s;
#pragma unroll
        for (int q = 0; q < 8; ++q) {
            const int idx = tid + 256 * q;        // 0..2047
            wd[(idx >> 4) * 17 + (idx & 15)] = wsrc[idx];
        }
    }
    if (tid < 32) ((float4*)b2s)[tid] = ((const float4*)(ws + WS_B2))[tid];
    __syncthreads();

    // preload all B-frags (W2 for this wave's 64 cols)
    short8 bfrag[4][4];
#pragma unroll
    for (int ct = 0; ct < 4; ++ct)
#pragma unroll
        for (int ks = 0; ks < 4; ++ks)
            bfrag[ct][ks] = *(const short8*)&w2s[(wc * 64 + ct * 16 + (lane & 15)) * 136 + ks * 32 + (lane >> 4) * 8];

    f32x4 acc[4][4];
#pragma unroll
    for (int rt = 0; rt < 4; ++rt)
#pragma unroll
        for (int ct = 0; ct < 4; ++ct) acc[rt][ct] = (f32x4){0.f, 0.f, 0.f, 0.f};

#pragma unroll
    for (int ks = 0; ks < 4; ++ks) {
        short8 af[4];
#pragma unroll
        for (int rt = 0; rt < 4; ++rt)
            af[rt] = *(const short8*)&qs[(wr * 64 + rt * 16 + (lane & 15)) * 136 + ks * 32 + (lane >> 4) * 8];
#pragma unroll
        for (int rt = 0; rt < 4; ++rt)
#pragma unroll
            for (int ct = 0; ct < 4; ++ct)
                acc[rt][ct] = __builtin_amdgcn_mfma_f32_16x16x32_bf16(af[rt], bfrag[ct][ks], acc[rt][ct], 0, 0, 0);
    }
    __syncthreads();

    // epilogue: 4 passes of 32 cols via LDS transpose (reuse qs as fp32 tmp)
    float* tmp = (float*)qs;   // [32][132]
#pragma unroll
    for (int cp = 0; cp < 4; ++cp) {
        if (wc == (cp >> 1)) {
#pragma unroll
            for (int rt = 0; rt < 4; ++rt)
#pragma unroll
                for (int tc = 0; tc < 2; ++tc) {
                    const int ct = (cp & 1) * 2 + tc;
                    const int cl = tc * 16 + (lane & 15);
                    const int r = wr * 64 + rt * 16 + (lane >> 4) * 4;
                    *(f32x4*)&tmp[cl * 132 + r] = acc[rt][ct];
                }
        }
        __syncthreads();
        {
            const int cl = tid >> 3;             // 0..31
            const int c = cp * 32 + cl;
            const float bb = b2s[c];
            float* __restrict__ col = out + (size_t)c * 65536 + rowbase;
#pragma unroll
            for (int ch = 0; ch < 4; ++ch) {
                const int r4 = (tid & 7) + ch * 8;   // 0..31
                float4 v = *(const float4*)&tmp[cl * 132 + r4 * 4];
                v.x += bb; v.y += bb; v.z += bb; v.w += bb;
                *(float4*)&col[r4 * 4] = v;
            }
        }
        __syncthreads();
    }
}

extern "C" void kernel_launch(void* const* d_in, const int* in_sizes, int n_in,
                              void* d_out, int out_size, void* d_ws, size_t ws_size,
                              hipStream_t stream) {
    const float* query = (const float*)d_in[0];
    const float* key   = (const float*)d_in[1];
    const float* value = (const float*)d_in[2];
    const float* Wq = (const float*)d_in[3];
    const float* bq = (const float*)d_in[4];
    const float* Wk = (const float*)d_in[5];
    const float* bk = (const float*)d_in[6];
    const float* Wv = (const float*)d_in[7];
    const float* bv = (const float*)d_in[8];
    float* out = (float*)d_out;
    float* ws  = (float*)d_ws;

    hipLaunchKernelGGL(kernelA, dim3(512), dim3(512), 0, stream, key, value, out);
    hipLaunchKernelGGL(kernelR, dim3(260), dim3(512), 0, stream, out, ws);
    hipLaunchKernelGGL(kernelB, dim3(4), dim3(512), 0, stream, Wk, bk, Wv, bv, Wq, bq, ws, out);
    hipLaunchKernelGGL(kernelC, dim3(512), dim3(256), 0, stream, query, ws, out);
}